// Round 13
// baseline (5395.909 us; speedup 1.0000x reference)
//
#include <hip/hip_runtime.h>

#define NBATCH 32
#define NPTS   100000
#define NDIM   6
#define KSEL   1024
#define BPB    8                  // blocks per batch
#define NTHREADS 1024
#define TOTT   (BPB * NTHREADS)   // 8192 threads per batch
#define PPT    13                 // ceil(NPTS / TOTT)
#define SLOT_WORDS 8              // 64B payload row per block (3 used)

// Exchange state: per-block payload rows (own 64B line) + ONE 32B tag line per
// batch/parity (8 u32). Writer: lane0 stores 3 payload u64 -> vmcnt(0) -> tag.
// Readers: one coalesced 8-lane load of the tag line per poll round (1 CP
// request/block/round vs R7's 8 lines x 48 lanes), one-shot payload read after.
struct Ws {
    unsigned long long pay[2][NBATCH][BPB][SLOT_WORDS]; // 32 KB
    unsigned tags[2][NBATCH][32];                       // 8 KB (128B row, 8 used)
};

__global__ void __launch_bounds__(1024) fps_init(unsigned long long* w) {
    int i = blockIdx.x * blockDim.x + threadIdx.x;
    if (i < (int)(sizeof(Ws) / 8)) w[i] = 0ull;
}

__global__ void __launch_bounds__(NTHREADS)
__attribute__((amdgpu_waves_per_eu(4, 4)))
fps_main(const float* __restrict__ pts,
         float* __restrict__ out,
         Ws* __restrict__ ws)
{
#pragma clang fp contract(off)
    const int bid   = blockIdx.x;
    const int batch = bid & (NBATCH - 1);
    const int blk   = bid >> 5;             // 0..7 within batch
    const int tid   = threadIdx.x;
    const int lane  = tid & 63;
    const int wav   = tid >> 6;             // 0..15
    const int tg    = blk * NTHREADS + tid; // 0..8191 within batch

    // pd in LDS: removes the 13xf64 register spill (R3-R12 carried ~208B/thread/iter
    // of L2-scratch traffic). Per-lane stride 8B = 2-way bank alias = free.
    __shared__ double pd_s[PPT][NTHREADS];          // 104 KB
    __shared__ double rdv[16];
    __shared__ int    rii[16];
    __shared__ float  rfx[16], rfy[16], rfz[16];
    __shared__ float  lsh[3];
    __shared__ int    idx_l[KSEL];                  // leader (blk==0) only
    __shared__ double fr0[16], fr1[16], fr2[16];
    __shared__ double sc[4];

    const float* base = pts + (size_t)batch * NPTS * NDIM;

    // ---- xyz in registers (39 VGPRs); dist state in LDS
    float px[PPT], py[PPT], pz[PPT];
#pragma unroll
    for (int k = 0; k < PPT; ++k) {
        int gi = k * TOTT + tg;
        if (gi < NPTS) {
            const float* p = base + (size_t)gi * NDIM;
            px[k] = p[0]; py[k] = p[1]; pz[k] = p[2];
            pd_s[k][tid] = 1e10;
        } else {
            px[k] = 0.f; py[k] = 0.f; pz[k] = 0.f;
            pd_s[k][tid] = -1.0;   // never wins (valid dists >= 0)
        }
    }

    double lx = (double)base[0], ly = (double)base[1], lz = (double)base[2]; // first = idx 0

    for (int t = 0; t < KSEL - 1; ++t) {
        const unsigned tag = (unsigned)(t + 1);
        const int par = t & 1;
        // ---- f64 distance update + thread-local argmax (numpy order, no FMA)
        double bd = -1.0; int bi = 0x7FFFFFFF;
        float bx = 0.f, by = 0.f, bz = 0.f;
#pragma unroll
        for (int k = 0; k < PPT; ++k) {
            double dx = (double)px[k] - lx;
            double dy = (double)py[k] - ly;
            double dz = (double)pz[k] - lz;
            double dd = ((dx * dx) + (dy * dy)) + (dz * dz);
            double nd = fmin(pd_s[k][tid], dd);
            pd_s[k][tid] = nd;
            if (nd > bd) { bd = nd; bi = k * TOTT + tg; bx = px[k]; by = py[k]; bz = pz[k]; }
        }
        // ---- wave reduce (dist desc, idx asc), carrying xyz
#pragma unroll
        for (int off = 32; off >= 1; off >>= 1) {
            double od = __shfl_xor(bd, off, 64);
            int    oi = __shfl_xor(bi, off, 64);
            float  ox = __shfl_xor(bx, off, 64);
            float  oy = __shfl_xor(by, off, 64);
            float  oz = __shfl_xor(bz, off, 64);
            if (od > bd || (od == bd && oi < bi)) { bd = od; bi = oi; bx = ox; by = oy; bz = oz; }
        }
        if (lane == 0) { rdv[wav] = bd; rii[wav] = bi; rfx[wav] = bx; rfy[wav] = by; rfz[wav] = bz; }
        __syncthreads();

        if (wav == 0) {
            // ---- block reduce over 16 wave winners
            double qd = (lane < 16) ? rdv[lane] : -2.0;
            int    qi = (lane < 16) ? rii[lane] : 0x7FFFFFFF;
            float  qx = (lane < 16) ? rfx[lane] : 0.f;
            float  qy = (lane < 16) ? rfy[lane] : 0.f;
            float  qz = (lane < 16) ? rfz[lane] : 0.f;
#pragma unroll
            for (int off = 8; off >= 1; off >>= 1) {
                double od = __shfl_xor(qd, off, 64);
                int    oi = __shfl_xor(qi, off, 64);
                float  ox = __shfl_xor(qx, off, 64);
                float  oy = __shfl_xor(qy, off, 64);
                float  oz = __shfl_xor(qz, off, 64);
                if (od > qd || (od == qd && oi < qi)) { qd = od; qi = oi; qx = ox; qy = oy; qz = oz; }
            }
            // ---- post: lane0 stores payload (3 u64, own line), vmcnt ack, then tag
            if (lane == 0) {
                unsigned long long db = (unsigned long long)__double_as_longlong(qd);
                unsigned long long xy = ((unsigned long long)__float_as_uint(qy) << 32)
                                      |  (unsigned long long)__float_as_uint(qx);
                unsigned long long zi = ((unsigned long long)(unsigned)qi << 32)
                                      |  (unsigned long long)__float_as_uint(qz);
                unsigned long long* prow = &ws->pay[par][batch][blk][0];
                __hip_atomic_store(&prow[0], db, __ATOMIC_RELAXED, __HIP_MEMORY_SCOPE_AGENT);
                __hip_atomic_store(&prow[1], xy, __ATOMIC_RELAXED, __HIP_MEMORY_SCOPE_AGENT);
                __hip_atomic_store(&prow[2], zi, __ATOMIC_RELAXED, __HIP_MEMORY_SCOPE_AGENT);
                asm volatile("s_waitcnt vmcnt(0)" ::: "memory");   // payload committed before tag
                __hip_atomic_store(&ws->tags[par][batch][blk], tag,
                                   __ATOMIC_RELAXED, __HIP_MEMORY_SCOPE_AGENT);
            }
            // ---- poll: ONE coalesced 8-lane load of the tag line per round
            unsigned* trow = &ws->tags[par][batch][0];
            for (;;) {
                unsigned v = 0u;
                if (lane < BPB) v = __hip_atomic_load(&trow[lane], __ATOMIC_RELAXED, __HIP_MEMORY_SCOPE_AGENT);
                int ok = (lane < BPB) ? (v == tag) : 1;
                if (__all(ok)) break;
            }
            asm volatile("" ::: "memory");   // payload loads stay after the poll
            // ---- one-shot payload read: 24 lanes, one u64 each
            unsigned long long pv = 0ull;
            if (lane < 3 * BPB) {
                int pb = lane / 3, pw = lane - pb * 3;
                pv = __hip_atomic_load(&ws->pay[par][batch][pb][pw],
                                       __ATOMIC_RELAXED, __HIP_MEMORY_SCOPE_AGENT);
            }
            // ---- assemble records into lanes 0..7
            int b3 = (lane < 8) ? lane * 3 : 0;
            unsigned long long d64 = __shfl(pv, b3,     64);
            unsigned long long pxy = __shfl(pv, b3 + 1, 64);
            unsigned long long pzi = __shfl(pv, b3 + 2, 64);
            double wd = __longlong_as_double((long long)d64);
            int    wi = (int)(pzi >> 32);
            float  wx = __uint_as_float((unsigned)(pxy & 0xFFFFFFFFull));
            float  wy = __uint_as_float((unsigned)(pxy >> 32));
            float  wz = __uint_as_float((unsigned)(pzi & 0xFFFFFFFFull));
            if (lane >= 8) { wd = -3.0; wi = 0x7FFFFFFF; }
#pragma unroll
            for (int off = 4; off >= 1; off >>= 1) {
                double od = __shfl_xor(wd, off, 64);
                int    oi = __shfl_xor(wi, off, 64);
                float  ox = __shfl_xor(wx, off, 64);
                float  oy = __shfl_xor(wy, off, 64);
                float  oz = __shfl_xor(wz, off, 64);
                if (od > wd || (od == wd && oi < wi)) { wd = od; wi = oi; wx = ox; wy = oy; wz = oz; }
            }
            if (lane == 0) {
                lsh[0] = wx; lsh[1] = wy; lsh[2] = wz;
                if (blk == 0) idx_l[t + 1] = wi;
            }
        }
        __syncthreads();
        lx = (double)lsh[0]; ly = (double)lsh[1]; lz = (double)lsh[2];
    }

    if (blk != 0) return;

    // ============ epilogue (leader block per batch): gather + normalize, f64 accumulation ============
    if (tid == 0) idx_l[0] = 0;
    __syncthreads();

    int si = idx_l[tid];
    const float* sp = base + (size_t)si * NDIM;
    float sx = sp[0], sy = sp[1], szv = sp[2];
    float f3 = sp[3], f4 = sp[4], f5 = sp[5];

    double rx = (double)sx, ry = (double)sy, rz = (double)szv;
#pragma unroll
    for (int off = 32; off >= 1; off >>= 1) {
        rx += __shfl_xor(rx, off, 64);
        ry += __shfl_xor(ry, off, 64);
        rz += __shfl_xor(rz, off, 64);
    }
    if (lane == 0) { fr0[wav] = rx; fr1[wav] = ry; fr2[wav] = rz; }
    __syncthreads();
    if (tid == 0) {
        double tx = 0., ty = 0., tz = 0.;
        for (int i = 0; i < 16; ++i) { tx += fr0[i]; ty += fr1[i]; tz += fr2[i]; }
        sc[0] = tx / (double)KSEL; sc[1] = ty / (double)KSEL; sc[2] = tz / (double)KSEL;
    }
    __syncthreads();
    double ax = (double)sx - sc[0], ay = (double)sy - sc[1], az = (double)szv - sc[2];
    double m = fmax(fabs(ax), fmax(fabs(ay), fabs(az)));
#pragma unroll
    for (int off = 32; off >= 1; off >>= 1) {
        double om = __shfl_xor(m, off, 64);
        m = fmax(m, om);
    }
    if (lane == 0) fr0[wav] = m;
    __syncthreads();
    if (tid == 0) {
        double mm = 0.;
        for (int i = 0; i < 16; ++i) mm = fmax(mm, fr0[i]);
        sc[3] = fmax(mm, 1e-6);
    }
    __syncthreads();
    double scale = sc[3];

    float* ob = out + ((size_t)batch * KSEL + tid) * NDIM;
    ob[0] = (float)(ax / scale);
    ob[1] = (float)(ay / scale);
    ob[2] = (float)(az / scale);
    ob[3] = f3; ob[4] = f4; ob[5] = f5;
}

extern "C" void kernel_launch(void* const* d_in, const int* in_sizes, int n_in,
                              void* d_out, int out_size, void* d_ws, size_t ws_size,
                              hipStream_t stream)
{
    const float* pts = (const float*)d_in[0];
    float* out = (float*)d_out;
    Ws* ws = (Ws*)d_ws;

    // re-zero tags/payloads every call: graph replays must not see stale tags
    int n64 = (int)(sizeof(Ws) / 8);
    hipLaunchKernelGGL(fps_init, dim3((n64 + 1023) / 1024), dim3(1024), 0, stream,
                       (unsigned long long*)d_ws);

    void* args[] = { (void*)&pts, (void*)&out, (void*)&ws };
    hipLaunchCooperativeKernel((void*)fps_main, dim3(NBATCH * BPB), dim3(NTHREADS),
                               args, 0, stream);
}

// Round 14
// 4578.237 us; speedup vs baseline: 1.1786x; 1.1786x over previous
//
#include <hip/hip_runtime.h>

#define NBATCH 32
#define NPTS   100000
#define NDIM   6
#define KSEL   1024
#define BPB    8                  // blocks per batch
#define NTHREADS 1024
#define TOTT   (BPB * NTHREADS)   // 8192 threads per batch
#define PPT    13                 // ceil(NPTS / TOTT)

// R6 protocol, ONE change: all exchange accesses are SYSTEM-scope relaxed.
// Agent-scope relaxed ops were served by the local XCD L2 (polls absent from
// FETCH_SIZE = L2 hits), so detect latency = lazy writeback + invalidate
// propagation (~1.5-2us). System scope (sc0 sc1 on the access) write-throughs
// the post and memory-side-services the poll -> detect = one true RTT.
// No acquire/release (no cache-maintenance instructions - R5's 17ms mistake).
struct __align__(32) BlkPost {            // 32 B per block post
    unsigned long long d_bits;            // f64 best distance (bit pattern)
    unsigned long long xy;                // f32 x | f32 y << 32
    unsigned long long z_idx;             // f32 z | i32 idx << 32
    unsigned long long pad;
};
struct __align__(64) FlagRow {            // one 64B line per batch per parity
    unsigned f[16];                       // f[0..7] used
};
struct Ws {
    BlkPost post[2][NBATCH][BPB];         // 16 KB
    FlagRow flags[2][NBATCH];             // 4 KB
};

__global__ void __launch_bounds__(1024) fps_init(unsigned int* w) {
    int i = blockIdx.x * blockDim.x + threadIdx.x;
    if (i < (int)(sizeof(Ws) / 4)) w[i] = 0u;
}

__global__ void __launch_bounds__(NTHREADS, 1) fps_main(const float* __restrict__ pts,
                                                        float* __restrict__ out,
                                                        Ws* __restrict__ ws)
{
#pragma clang fp contract(off)
    const int bid   = blockIdx.x;
    const int batch = bid & (NBATCH - 1);
    const int blk   = bid >> 5;             // 0..7 within batch
    const int tid   = threadIdx.x;
    const int lane  = tid & 63;
    const int wav   = tid >> 6;             // 0..15
    const int tg    = blk * NTHREADS + tid; // 0..8191 within batch

    __shared__ double rdv[16];
    __shared__ int    rii[16];
    __shared__ float  lsh[3];               // broadcast winner xyz
    __shared__ int    idx_l[KSEL];          // leader (blk==0) only
    __shared__ double fr0[16], fr1[16], fr2[16];
    __shared__ double sc[4];

    const float* base = pts + (size_t)batch * NPTS * NDIM;

    // ---- point state in registers; dist in f64 (bit-exact vs numpy f64 FPS)
    float  px[PPT], py[PPT], pz[PPT];
    double pd[PPT];
#pragma unroll
    for (int k = 0; k < PPT; ++k) {
        int gi = k * TOTT + tg;
        if (gi < NPTS) {
            const float* p = base + (size_t)gi * NDIM;
            px[k] = p[0]; py[k] = p[1]; pz[k] = p[2];
            pd[k] = 1e10;
        } else {
            px[k] = 0.f; py[k] = 0.f; pz[k] = 0.f;
            pd[k] = -1.0;   // never wins (valid dists >= 0)
        }
    }

    double lx = (double)base[0], ly = (double)base[1], lz = (double)base[2]; // first = idx 0

    for (int t = 0; t < KSEL - 1; ++t) {
        const unsigned tag = (unsigned)(t + 1);
        const int par = t & 1;
        // ---- f64 distance update + thread-local argmax (numpy order: (xx+yy)+zz, no FMA)
        double bd = -1.0; int bi = 0x7FFFFFFF;
#pragma unroll
        for (int k = 0; k < PPT; ++k) {
            double dx = (double)px[k] - lx;
            double dy = (double)py[k] - ly;
            double dz = (double)pz[k] - lz;
            double dd = ((dx * dx) + (dy * dy)) + (dz * dz);
            double nd = fmin(pd[k], dd);
            pd[k] = nd;
            if (nd > bd) { bd = nd; bi = k * TOTT + tg; }  // strict >: first max in-thread
        }
        // ---- wave reduce (dist desc, idx asc)
#pragma unroll
        for (int off = 32; off >= 1; off >>= 1) {
            double od = __shfl_xor(bd, off, 64);
            int    oi = __shfl_xor(bi, off, 64);
            if (od > bd || (od == bd && oi < bi)) { bd = od; bi = oi; }
        }
        if (lane == 0) { rdv[wav] = bd; rii[wav] = bi; }
        __syncthreads();

        if (wav == 0) {
            // ---- block reduce over 16 wave winners (lanes 0..15 hold them)
            double qd = (lane < 16) ? rdv[lane] : -2.0;
            int    qi = (lane < 16) ? rii[lane] : 0x7FFFFFFF;
#pragma unroll
            for (int off = 8; off >= 1; off >>= 1) {
                double od = __shfl_xor(qd, off, 64);
                int    oi = __shfl_xor(qi, off, 64);
                if (od > qd || (od == qd && oi < qi)) { qd = od; qi = oi; }
            }
            // ---- post: relaxed SYSTEM payload stores, vmcnt ack, relaxed SYSTEM flag
            if (lane == 0) {
                const float* wp = base + (size_t)qi * NDIM;   // L2-resident
                unsigned long long db = (unsigned long long)__double_as_longlong(qd);
                unsigned long long xy = ((unsigned long long)__float_as_uint(wp[1]) << 32)
                                      |  (unsigned long long)__float_as_uint(wp[0]);
                unsigned long long zi = ((unsigned long long)(unsigned)qi << 32)
                                      |  (unsigned long long)__float_as_uint(wp[2]);
                BlkPost* p = &ws->post[par][batch][blk];
                __hip_atomic_store(&p->d_bits, db, __ATOMIC_RELAXED, __HIP_MEMORY_SCOPE_SYSTEM);
                __hip_atomic_store(&p->xy,     xy, __ATOMIC_RELAXED, __HIP_MEMORY_SCOPE_SYSTEM);
                __hip_atomic_store(&p->z_idx,  zi, __ATOMIC_RELAXED, __HIP_MEMORY_SCOPE_SYSTEM);
                // store-release without cache-maintenance: wait for payload store acks,
                // then publish the tag (write-through).
                asm volatile("s_waitcnt vmcnt(0)" ::: "memory");
                __hip_atomic_store(&ws->flags[par][batch].f[blk], tag,
                                   __ATOMIC_RELAXED, __HIP_MEMORY_SCOPE_SYSTEM);
            }
            // ---- single-hop: lanes 0..7 spin on the 8 flags (memory-side-serviced loads)
            double wd_; int wi_; unsigned long long pxy, pzi;
            if (lane < BPB) {
                unsigned* fp = &ws->flags[par][batch].f[lane];
                while (__hip_atomic_load(fp, __ATOMIC_RELAXED, __HIP_MEMORY_SCOPE_SYSTEM) != tag) {}
                asm volatile("" ::: "memory");   // keep payload loads after the poll
                BlkPost* p = &ws->post[par][batch][lane];
                unsigned long long db = __hip_atomic_load(&p->d_bits, __ATOMIC_RELAXED, __HIP_MEMORY_SCOPE_SYSTEM);
                pxy = __hip_atomic_load(&p->xy,    __ATOMIC_RELAXED, __HIP_MEMORY_SCOPE_SYSTEM);
                pzi = __hip_atomic_load(&p->z_idx, __ATOMIC_RELAXED, __HIP_MEMORY_SCOPE_SYSTEM);
                wd_ = __longlong_as_double((long long)db);
                wi_ = (int)(pzi >> 32);
            } else { wd_ = -3.0; wi_ = 0x7FFFFFFF; pxy = 0ull; pzi = 0ull; }
#pragma unroll
            for (int off = 4; off >= 1; off >>= 1) {   // reduce within lanes 0..7
                double od = __shfl_xor(wd_, off, 64);
                int    oi = __shfl_xor(wi_, off, 64);
                unsigned long long oxy = __shfl_xor(pxy, off, 64);
                unsigned long long ozi = __shfl_xor(pzi, off, 64);
                if (od > wd_ || (od == wd_ && oi < wi_)) { wd_ = od; wi_ = oi; pxy = oxy; pzi = ozi; }
            }
            if (lane == 0) {
                lsh[0] = __uint_as_float((unsigned)(pxy & 0xFFFFFFFFull));
                lsh[1] = __uint_as_float((unsigned)(pxy >> 32));
                lsh[2] = __uint_as_float((unsigned)(pzi & 0xFFFFFFFFull));
                if (blk == 0) idx_l[t + 1] = wi_;
            }
        }
        __syncthreads();
        lx = (double)lsh[0]; ly = (double)lsh[1]; lz = (double)lsh[2];
    }

    if (blk != 0) return;

    // ============ epilogue (leader block per batch): gather + normalize, f64 accumulation ============
    if (tid == 0) idx_l[0] = 0;
    __syncthreads();

    int si = idx_l[tid];
    const float* sp = base + (size_t)si * NDIM;
    float sx = sp[0], sy = sp[1], szv = sp[2];
    float f3 = sp[3], f4 = sp[4], f5 = sp[5];

    double rx = (double)sx, ry = (double)sy, rz = (double)szv;
#pragma unroll
    for (int off = 32; off >= 1; off >>= 1) {
        rx += __shfl_xor(rx, off, 64);
        ry += __shfl_xor(ry, off, 64);
        rz += __shfl_xor(rz, off, 64);
    }
    if (lane == 0) { fr0[wav] = rx; fr1[wav] = ry; fr2[wav] = rz; }
    __syncthreads();
    if (tid == 0) {
        double tx = 0., ty = 0., tz = 0.;
        for (int i = 0; i < 16; ++i) { tx += fr0[i]; ty += fr1[i]; tz += fr2[i]; }
        sc[0] = tx / (double)KSEL; sc[1] = ty / (double)KSEL; sc[2] = tz / (double)KSEL;
    }
    __syncthreads();
    double ax = (double)sx - sc[0], ay = (double)sy - sc[1], az = (double)szv - sc[2];
    double m = fmax(fabs(ax), fmax(fabs(ay), fabs(az)));
#pragma unroll
    for (int off = 32; off >= 1; off >>= 1) {
        double om = __shfl_xor(m, off, 64);
        m = fmax(m, om);
    }
    if (lane == 0) fr0[wav] = m;
    __syncthreads();
    if (tid == 0) {
        double mm = 0.;
        for (int i = 0; i < 16; ++i) mm = fmax(mm, fr0[i]);
        sc[3] = fmax(mm, 1e-6);
    }
    __syncthreads();
    double scale = sc[3];

    float* ob = out + ((size_t)batch * KSEL + tid) * NDIM;
    ob[0] = (float)(ax / scale);
    ob[1] = (float)(ay / scale);
    ob[2] = (float)(az / scale);
    ob[3] = f3; ob[4] = f4; ob[5] = f5;
}

extern "C" void kernel_launch(void* const* d_in, const int* in_sizes, int n_in,
                              void* d_out, int out_size, void* d_ws, size_t ws_size,
                              hipStream_t stream)
{
    const float* pts = (const float*)d_in[0];
    float* out = (float*)d_out;
    Ws* ws = (Ws*)d_ws;

    // re-zero flags/payloads every call (graph replays must not see stale tags)
    hipLaunchKernelGGL(fps_init, dim3(8), dim3(1024), 0, stream, (unsigned int*)d_ws);

    void* args[] = { (void*)&pts, (void*)&out, (void*)&ws };
    hipLaunchCooperativeKernel((void*)fps_main, dim3(NBATCH * BPB), dim3(NTHREADS),
                               args, 0, stream);
}

// Round 15
// 3936.744 us; speedup vs baseline: 1.3707x; 1.1630x over previous
//
#include <hip/hip_runtime.h>

#define NBATCH 32
#define NPTS   100000
#define NDIM   6
#define KSEL   1024
#define BPB    8                  // blocks per batch
#define NTHREADS 1024
#define TOTT   (BPB * NTHREADS)   // 8192 threads per batch
#define PPT    13                 // ceil(NPTS / TOTT)
#define MASK51 ((1ull << 51) - 1)

// Single-leg exchange: per block, TWO self-validating words (13b tag | 51b payload).
//   w0 = tag<<51 | dist_bits[62:12]        (dist >= 0 -> bit 63 always 0)
//   w1 = tag<<51 | dist_bits[11:0]<<17 | idx17
// No flag, no vmcnt fence: each word validates itself, no inter-word ordering
// needed. Winner xyz is NOT shipped: readers gather from pts (L2-resident).
// Parity-2 slot sets, monotone tags (<=1023, 13 bits never wrap), init-zeroed.
struct Ws {
    unsigned long long w[2][NBATCH][16];   // 8 KB; 16 words = 2 lines per batch/parity
};

__global__ void __launch_bounds__(1024) fps_init(unsigned long long* w) {
    int i = blockIdx.x * blockDim.x + threadIdx.x;
    if (i < (int)(sizeof(Ws) / 8)) w[i] = 0ull;
}

__global__ void __launch_bounds__(NTHREADS, 1) fps_main(const float* __restrict__ pts,
                                                        float* __restrict__ out,
                                                        Ws* __restrict__ ws)
{
#pragma clang fp contract(off)
    const int bid   = blockIdx.x;
    const int batch = bid & (NBATCH - 1);
    const int blk   = bid >> 5;             // 0..7 within batch
    const int tid   = threadIdx.x;
    const int lane  = tid & 63;
    const int wav   = tid >> 6;             // 0..15
    const int tg    = blk * NTHREADS + tid; // 0..8191 within batch

    __shared__ double rdv[16];
    __shared__ int    rii[16];
    __shared__ float  lsh[3];               // broadcast winner xyz
    __shared__ int    idx_l[KSEL];          // leader (blk==0) only
    __shared__ double fr0[16], fr1[16], fr2[16];
    __shared__ double sc[4];

    const float* base = pts + (size_t)batch * NPTS * NDIM;

    // ---- point state in registers; dist in f64 (bit-exact vs numpy f64 FPS)
    float  px[PPT], py[PPT], pz[PPT];
    double pd[PPT];
#pragma unroll
    for (int k = 0; k < PPT; ++k) {
        int gi = k * TOTT + tg;
        if (gi < NPTS) {
            const float* p = base + (size_t)gi * NDIM;
            px[k] = p[0]; py[k] = p[1]; pz[k] = p[2];
            pd[k] = 1e10;
        } else {
            px[k] = 0.f; py[k] = 0.f; pz[k] = 0.f;
            pd[k] = -1.0;   // never wins (valid dists >= 0)
        }
    }

    double lx = (double)base[0], ly = (double)base[1], lz = (double)base[2]; // first = idx 0

    for (int t = 0; t < KSEL - 1; ++t) {
        const unsigned long long tag = (unsigned long long)(t + 1);   // <= 1023, fits 13b
        const int par = t & 1;
        // ---- f64 distance update + thread-local argmax (numpy order: (xx+yy)+zz, no FMA)
        double bd = -1.0; int bi = 0x7FFFFFFF;
#pragma unroll
        for (int k = 0; k < PPT; ++k) {
            double dx = (double)px[k] - lx;
            double dy = (double)py[k] - ly;
            double dz = (double)pz[k] - lz;
            double dd = ((dx * dx) + (dy * dy)) + (dz * dz);
            double nd = fmin(pd[k], dd);
            pd[k] = nd;
            if (nd > bd) { bd = nd; bi = k * TOTT + tg; }  // strict >: first max in-thread
        }
        // ---- wave reduce (dist desc, idx asc)
#pragma unroll
        for (int off = 32; off >= 1; off >>= 1) {
            double od = __shfl_xor(bd, off, 64);
            int    oi = __shfl_xor(bi, off, 64);
            if (od > bd || (od == bd && oi < bi)) { bd = od; bi = oi; }
        }
        if (lane == 0) { rdv[wav] = bd; rii[wav] = bi; }
        __syncthreads();

        if (wav == 0) {
            // ---- block reduce over 16 wave winners (lanes 0..15 hold them)
            double qd = (lane < 16) ? rdv[lane] : -2.0;
            int    qi = (lane < 16) ? rii[lane] : 0x7FFFFFFF;
#pragma unroll
            for (int off = 8; off >= 1; off >>= 1) {
                double od = __shfl_xor(qd, off, 64);
                int    oi = __shfl_xor(qi, off, 64);
                if (od > qd || (od == qd && oi < qi)) { qd = od; qi = oi; }
            }
            // ---- post: lanes 0..1 fire the two self-validating words (one wave-store, no fence)
            unsigned long long db = (unsigned long long)__double_as_longlong(qd); // bit63 == 0
            unsigned long long w0 = (tag << 51) | (db >> 12);
            unsigned long long w1 = (tag << 51) | ((db & 0xFFFull) << 17)
                                  | (unsigned long long)(unsigned)qi;
            unsigned long long* brow = &ws->w[par][batch][0];
            if (lane < 2)
                __hip_atomic_store(&brow[blk * 2 + lane], (lane == 0) ? w0 : w1,
                                   __ATOMIC_RELAXED, __HIP_MEMORY_SCOPE_SYSTEM);
            // ---- poll: 16 lanes, one word each; payload arrives WITH detection
            unsigned long long v = 0ull;
            for (;;) {
                if (lane < 16)
                    v = __hip_atomic_load(&brow[lane], __ATOMIC_RELAXED, __HIP_MEMORY_SCOPE_SYSTEM);
                int ok = (lane < 16) ? ((v >> 51) == tag) : 1;
                if (__all(ok)) break;
            }
            // ---- assemble per-block records into lanes (block b -> lanes holding b = lane&7)
            unsigned long long p0 = __shfl(v, (lane & 7) * 2,     64) & MASK51;
            unsigned long long p1 = __shfl(v, (lane & 7) * 2 + 1, 64) & MASK51;
            unsigned long long rdb = (p0 << 12) | (p1 >> 17);
            int ridx = (int)(p1 & 0x1FFFFull);
            // ---- reduce 8 blocks: u64 compare == f64 compare for nonneg dists
#pragma unroll
            for (int off = 4; off >= 1; off >>= 1) {
                unsigned long long od = __shfl_xor(rdb, off, 64);
                int                oi = __shfl_xor(ridx, off, 64);
                if (od > rdb || (od == rdb && oi < ridx)) { rdb = od; ridx = oi; }
            }
            if (lane == 0) {
                const float* wp = base + (size_t)ridx * NDIM;   // read-only, local-L2 resident
                lsh[0] = wp[0]; lsh[1] = wp[1]; lsh[2] = wp[2];
                if (blk == 0) idx_l[t + 1] = ridx;
            }
        }
        __syncthreads();
        lx = (double)lsh[0]; ly = (double)lsh[1]; lz = (double)lsh[2];
    }

    if (blk != 0) return;

    // ============ epilogue (leader block per batch): gather + normalize, f64 accumulation ============
    if (tid == 0) idx_l[0] = 0;
    __syncthreads();

    int si = idx_l[tid];
    const float* sp = base + (size_t)si * NDIM;
    float sx = sp[0], sy = sp[1], szv = sp[2];
    float f3 = sp[3], f4 = sp[4], f5 = sp[5];

    double rx = (double)sx, ry = (double)sy, rz = (double)szv;
#pragma unroll
    for (int off = 32; off >= 1; off >>= 1) {
        rx += __shfl_xor(rx, off, 64);
        ry += __shfl_xor(ry, off, 64);
        rz += __shfl_xor(rz, off, 64);
    }
    if (lane == 0) { fr0[wav] = rx; fr1[wav] = ry; fr2[wav] = rz; }
    __syncthreads();
    if (tid == 0) {
        double tx = 0., ty = 0., tz = 0.;
        for (int i = 0; i < 16; ++i) { tx += fr0[i]; ty += fr1[i]; tz += fr2[i]; }
        sc[0] = tx / (double)KSEL; sc[1] = ty / (double)KSEL; sc[2] = tz / (double)KSEL;
    }
    __syncthreads();
    double ax = (double)sx - sc[0], ay = (double)sy - sc[1], az = (double)szv - sc[2];
    double m = fmax(fabs(ax), fmax(fabs(ay), fabs(az)));
#pragma unroll
    for (int off = 32; off >= 1; off >>= 1) {
        double om = __shfl_xor(m, off, 64);
        m = fmax(m, om);
    }
    if (lane == 0) fr0[wav] = m;
    __syncthreads();
    if (tid == 0) {
        double mm = 0.;
        for (int i = 0; i < 16; ++i) mm = fmax(mm, fr0[i]);
        sc[3] = fmax(mm, 1e-6);
    }
    __syncthreads();
    double scale = sc[3];

    float* ob = out + ((size_t)batch * KSEL + tid) * NDIM;
    ob[0] = (float)(ax / scale);
    ob[1] = (float)(ay / scale);
    ob[2] = (float)(az / scale);
    ob[3] = f3; ob[4] = f4; ob[5] = f5;
}

extern "C" void kernel_launch(void* const* d_in, const int* in_sizes, int n_in,
                              void* d_out, int out_size, void* d_ws, size_t ws_size,
                              hipStream_t stream)
{
    const float* pts = (const float*)d_in[0];
    float* out = (float*)d_out;
    Ws* ws = (Ws*)d_ws;

    // re-zero slot words every call (graph replays must not see stale tags)
    hipLaunchKernelGGL(fps_init, dim3(1), dim3(1024), 0, stream, (unsigned long long*)d_ws);

    void* args[] = { (void*)&pts, (void*)&out, (void*)&ws };
    hipLaunchCooperativeKernel((void*)fps_main, dim3(NBATCH * BPB), dim3(NTHREADS),
                               args, 0, stream);
}